// Round 1
// baseline (15178.059 us; speedup 1.0000x reference)
//
#include <hip/hip_runtime.h>
#include <math.h>

#define Bb 256
#define Tt 256
#define Ff 128
#define Hh 512
#define KTOT 768   // 2F+H
#define NC 2048    // 4*H  (r, z, i_n, h_n per colH)

// ---------------- ws layout (floats) ----------------
// gamma : Tt*Bb*Hh            = 33554432   (134.2 MB)  [T,B,H] time-major
// wcomb : NC*KTOT             =  1572864   (6.3 MB)    [colH*4+gate][768]
// biasc : NC                  =     2048
// hbuf  : 2*Bb*Hh             =   262144   (ping-pong)
// total = 35391488 floats = 141.6 MB
#define WS_GAMMA 0
#define WS_WCOMB 33554432
#define WS_BIASC (WS_WCOMB + 1572864)
#define WS_HBUF  (WS_BIASC + 2048)

__global__ __launch_bounds__(256) void k_zero(float* p, int n) {
    int i = blockIdx.x * 256 + threadIdx.x;
    if (i < n) p[i] = 0.f;
}

// Build combined weight + bias.
// gate g: 0=r, 1=z, 2=i_n, 3=h_n.  Row c = colH*4 + g, K = 768 = [x(128) | h(512) | m(128)]
__global__ __launch_bounds__(256) void k_wcomb(const float* __restrict__ W_ih,
                                               const float* __restrict__ W_hh,
                                               const float* __restrict__ b_ih,
                                               const float* __restrict__ b_hh,
                                               float* __restrict__ wcomb,
                                               float* __restrict__ biasc) {
    int idx = blockIdx.x * 256 + threadIdx.x;   // < NC*KTOT (exact)
    int k = idx % KTOT;
    int c = idx / KTOT;
    int g = c & 3, j = c >> 2;
    float w;
    if (g < 3) {
        w = W_ih[(g * Hh + j) * KTOT + k];
        if (g < 2 && k >= Ff && k < Ff + Hh) w += W_hh[(g * Hh + j) * Hh + (k - Ff)];
    } else {
        w = (k >= Ff && k < Ff + Hh) ? W_hh[(2 * Hh + j) * Hh + (k - Ff)] : 0.f;
    }
    wcomb[idx] = w;
    if (k == 0) {
        float bv;
        if (g == 0)      bv = b_ih[j] + b_hh[j];
        else if (g == 1) bv = b_ih[Hh + j] + b_hh[Hh + j];
        else if (g == 2) bv = b_ih[2 * Hh + j];
        else             bv = b_hh[2 * Hh + j];
        biasc[c] = bv;
    }
}

// gamma_h precompute: gamma[t*B+b][j] = exp(-relu(deltas[b,t,:] . Wh[j,:] + bh[j]))
// GEMM: rows = 65536 (bt, time-major), cols = 512, K = 128. Tile 64x64, KC=64, micro 4x4.
__global__ __launch_bounds__(256) void k_gamma(const float* __restrict__ deltas,
                                               const float* __restrict__ Wh,
                                               const float* __restrict__ bh,
                                               float* __restrict__ gamma) {
    __shared__ float A_s[64][68];  // [row][kk]
    __shared__ float B_s[64][68];  // [col][kk]
    int tid = threadIdx.x;
    int tx = tid & 15, ty = tid >> 4;
    int bt0 = blockIdx.x * 64;
    int c0  = blockIdx.y * 64;

    float acc[4][4];
#pragma unroll
    for (int i = 0; i < 4; ++i)
#pragma unroll
        for (int j = 0; j < 4; ++j) acc[i][j] = 0.f;

    for (int kc = 0; kc < 2; ++kc) {
        // stage A: 64 rows x 64 k = 1024 float4, contiguous stores (no transpose)
#pragma unroll
        for (int s = 0; s < 4; ++s) {
            int v = tid + s * 256;
            int row = v >> 4, c4 = v & 15, kk = c4 * 4;
            int bt = bt0 + row;
            int b = bt & 255, tt = bt >> 8;
            float4 a = *(const float4*)&deltas[b * (Tt * Ff) + tt * Ff + kc * 64 + kk];
            *(float4*)&A_s[row][kk] = a;
        }
#pragma unroll
        for (int s = 0; s < 4; ++s) {
            int v = tid + s * 256;
            int col = v >> 4, c4 = v & 15, kk = c4 * 4;
            float4 w = *(const float4*)&Wh[(c0 + col) * Ff + kc * 64 + kk];
            *(float4*)&B_s[col][kk] = w;
        }
        __syncthreads();
#pragma unroll
        for (int kk = 0; kk < 64; kk += 4) {
            float4 a[4], b[4];
#pragma unroll
            for (int i = 0; i < 4; ++i) a[i] = *(const float4*)&A_s[4 * ty + i][kk];
#pragma unroll
            for (int j = 0; j < 4; ++j) b[j] = *(const float4*)&B_s[4 * tx + j][kk];
#pragma unroll
            for (int i = 0; i < 4; ++i)
#pragma unroll
                for (int j = 0; j < 4; ++j) {
                    acc[i][j] += a[i].x * b[j].x;
                    acc[i][j] += a[i].y * b[j].y;
                    acc[i][j] += a[i].z * b[j].z;
                    acc[i][j] += a[i].w * b[j].w;
                }
        }
        __syncthreads();
    }
#pragma unroll
    for (int i = 0; i < 4; ++i) {
        int bt = bt0 + 4 * ty + i;
#pragma unroll
        for (int j = 0; j < 4; ++j) {
            int col = c0 + 4 * tx + j;
            float x = acc[i][j] + bh[col];
            gamma[bt * Hh + col] = expf(-fmaxf(x, 0.f));
        }
    }
}

__device__ __forceinline__ float xrep_one(float x, float m, float d, float l,
                                          float w, float bb, float em) {
    float gx = expf(-fmaxf(d * w + bb, 0.f));
    float xh = gx * l + (1.f - gx) * em;
    return m * x + (1.f - m) * xh;
}

// Per-step kernel: C[256 x 2048] = inp[256 x 768] @ Wcomb^T, then gates + h update.
// Grid (32 colH-groups, 8 row-groups). Tile: 32 rows x 16 colH (64 wcols). KC=64. Micro 2x4.
__global__ __launch_bounds__(256) void k_step(int t,
                                              const float* __restrict__ values,
                                              const float* __restrict__ masks,
                                              const float* __restrict__ deltas,
                                              const float* __restrict__ locf,
                                              const float* __restrict__ emean,
                                              const float* __restrict__ wx,
                                              const float* __restrict__ bx,
                                              const float* __restrict__ gamma,
                                              const float* __restrict__ wcomb,
                                              const float* __restrict__ biasc,
                                              const float* __restrict__ hprev,
                                              float* __restrict__ hnext,
                                              float* __restrict__ hs,
                                              float* __restrict__ hlast) {
    __shared__ float A_s[32][68];  // [row][kk]
    __shared__ float W_s[64][68];  // [col][kk]
    int tid = threadIdx.x;
    int tx = tid & 15, ty = tid >> 4;
    int c0  = blockIdx.x * 16;   // colH base
    int wc0 = c0 * 4;            // weight-row base
    int r0  = blockIdx.y * 32;   // batch-row base

    float acc[2][4];
#pragma unroll
    for (int i = 0; i < 2; ++i)
#pragma unroll
        for (int j = 0; j < 4; ++j) acc[i][j] = 0.f;

    for (int kc = 0; kc < 12; ++kc) {
        // ---- stage A tile: 32 rows x 64 k = 512 float4, 2 per thread ----
#pragma unroll
        for (int s = 0; s < 2; ++s) {
            int v = tid + s * 256;
            int row = v >> 4, c4 = v & 15, kk = c4 * 4;
            int b = r0 + row;
            int kglob = kc * 64 + kk;
            float4 a;
            if (kc < 2) {
                // x_rep computed inline
                int fo = kglob;                       // 0..127
                int go = b * (Tt * Ff) + t * Ff + fo;
                float4 xv = *(const float4*)&values[go];
                float4 mv = *(const float4*)&masks[go];
                float4 dv = *(const float4*)&deltas[go];
                float4 lv = *(const float4*)&locf[go];
                float4 wv = *(const float4*)&wx[fo];
                float4 bv = *(const float4*)&bx[fo];
                float4 ev = *(const float4*)&emean[fo];
                a.x = xrep_one(xv.x, mv.x, dv.x, lv.x, wv.x, bv.x, ev.x);
                a.y = xrep_one(xv.y, mv.y, dv.y, lv.y, wv.y, bv.y, ev.y);
                a.z = xrep_one(xv.z, mv.z, dv.z, lv.z, wv.z, bv.z, ev.z);
                a.w = xrep_one(xv.w, mv.w, dv.w, lv.w, wv.w, bv.w, ev.w);
            } else if (kc < 10) {
                int hi = kglob - 128;                 // 0..511
                float4 hp = *(const float4*)&hprev[b * Hh + hi];
                float4 gm = *(const float4*)&gamma[(t * Bb + b) * Hh + hi];
                a.x = hp.x * gm.x; a.y = hp.y * gm.y; a.z = hp.z * gm.z; a.w = hp.w * gm.w;
            } else {
                int fo = kglob - 640;                 // 0..127
                a = *(const float4*)&masks[b * (Tt * Ff) + t * Ff + fo];
            }
            *(float4*)&A_s[row][kk] = a;
        }
        // ---- stage W tile: 64 cols x 64 k = 1024 float4, 4 per thread ----
#pragma unroll
        for (int s = 0; s < 4; ++s) {
            int v = tid + s * 256;
            int col = v >> 4, c4 = v & 15, kk = c4 * 4;
            float4 w = *(const float4*)&wcomb[(wc0 + col) * KTOT + kc * 64 + kk];
            *(float4*)&W_s[col][kk] = w;
        }
        __syncthreads();
        // ---- compute: micro 2 rows x 4 gate-cols ----
#pragma unroll
        for (int kk = 0; kk < 64; kk += 4) {
            float4 a0 = *(const float4*)&A_s[2 * ty + 0][kk];
            float4 a1 = *(const float4*)&A_s[2 * ty + 1][kk];
            float4 w[4];
#pragma unroll
            for (int j = 0; j < 4; ++j) w[j] = *(const float4*)&W_s[4 * tx + j][kk];
#pragma unroll
            for (int j = 0; j < 4; ++j) {
                acc[0][j] += a0.x * w[j].x; acc[0][j] += a0.y * w[j].y;
                acc[0][j] += a0.z * w[j].z; acc[0][j] += a0.w * w[j].w;
                acc[1][j] += a1.x * w[j].x; acc[1][j] += a1.y * w[j].y;
                acc[1][j] += a1.z * w[j].z; acc[1][j] += a1.w * w[j].w;
            }
        }
        __syncthreads();
    }

    // ---- epilogue: gates + h update ----
    int jH = c0 + tx;
    float4 bi = *(const float4*)&biasc[jH * 4];
#pragma unroll
    for (int i = 0; i < 2; ++i) {
        int b = r0 + 2 * ty + i;
        float rr = 1.f / (1.f + expf(-(acc[i][0] + bi.x)));
        float zz = 1.f / (1.f + expf(-(acc[i][1] + bi.y)));
        float nn = tanhf(acc[i][2] + bi.z + rr * (acc[i][3] + bi.w));
        float hp = hprev[b * Hh + jH] * gamma[(t * Bb + b) * Hh + jH];
        float hn = (1.f - zz) * nn + zz * hp;
        hnext[b * Hh + jH] = hn;
        hs[b * (Tt * Hh) + t * Hh + jH] = hn;
        if (t == Tt - 1) hlast[b * Hh + jH] = hn;
    }
}

extern "C" void kernel_launch(void* const* d_in, const int* in_sizes, int n_in,
                              void* d_out, int out_size, void* d_ws, size_t ws_size,
                              hipStream_t stream) {
    const float* values = (const float*)d_in[0];
    const float* masks  = (const float*)d_in[1];
    const float* deltas = (const float*)d_in[2];
    const float* emean  = (const float*)d_in[3];
    const float* locf   = (const float*)d_in[4];
    const float* wx     = (const float*)d_in[5];
    const float* bx     = (const float*)d_in[6];
    const float* Wh     = (const float*)d_in[7];
    const float* bh     = (const float*)d_in[8];
    const float* W_ih   = (const float*)d_in[9];
    const float* W_hh   = (const float*)d_in[10];
    const float* b_ih   = (const float*)d_in[11];
    const float* b_hh   = (const float*)d_in[12];

    float* ws    = (float*)d_ws;
    float* gamma = ws + WS_GAMMA;
    float* wcomb = ws + WS_WCOMB;
    float* biasc = ws + WS_BIASC;
    float* hbuf  = ws + WS_HBUF;
    float* hs    = (float*)d_out;
    float* hlast = hs + Bb * Tt * Hh;

    // h0 = 0 (ws is poisoned 0xAA before every timed launch)
    k_zero<<<(Bb * Hh + 255) / 256, 256, 0, stream>>>(hbuf, Bb * Hh);
    // parallel precompute
    k_gamma<<<dim3((Tt * Bb) / 64, Hh / 64), 256, 0, stream>>>(deltas, Wh, bh, gamma);
    k_wcomb<<<(NC * KTOT) / 256, 256, 0, stream>>>(W_ih, W_hh, b_ih, b_hh, wcomb, biasc);
    // sequential scan
    for (int t = 0; t < Tt; ++t) {
        float* hprev = hbuf + (t & 1) * (Bb * Hh);
        float* hnext = hbuf + ((t + 1) & 1) * (Bb * Hh);
        k_step<<<dim3(Hh / 16, Bb / 32), 256, 0, stream>>>(
            t, values, masks, deltas, locf, emean, wx, bx,
            gamma, wcomb, biasc, hprev, hnext, hs, hlast);
    }
}

// Round 2
// 2535.305 us; speedup vs baseline: 5.9867x; 5.9867x over previous
//
#include <hip/hip_runtime.h>
#include <math.h>

#define Bb 256
#define Tt 256
#define Ff 128
#define Hh 512
#define KTOT 768   // 2F+H
#define NC 2048    // 4*H  (gate cols: colH*4 + {r,z,i_n,h_n})

typedef unsigned short u16;
typedef unsigned int   u32;
typedef __attribute__((ext_vector_type(8))) short s8v;   // 8 bf16 (4 VGPRs)
typedef __attribute__((ext_vector_type(4))) float f4v;   // 4 fp32 acc

// ---------------- ws layout (bytes) ----------------
// gamma  : u16 [Tt*Bb*Hh]        = 67,108,864 B   [T,B,H]
// xrep   : u16 [Bb*Tt*Ff]        = 16,777,216 B
// mbf    : u16 [Bb*Tt*Ff]        = 16,777,216 B
// wfrag  : u16 [NC*KTOT]         =  3,145,728 B   frag-major (see k_wcomb)
// biasc  : f32 [NC]              =      8,192 B
// hbuf   : f32 [2*Bb*Hh]         =  1,048,576 B   ping-pong
// total ≈ 105 MB  (< 141.6 MB proven in round 1)
#define OFF_GAMMA 0ull
#define OFF_XREP  (OFF_GAMMA + 67108864ull)
#define OFF_MBF   (OFF_XREP  + 16777216ull)
#define OFF_WFRAG (OFF_MBF   + 16777216ull)
#define OFF_BIASC (OFF_WFRAG + 3145728ull)
#define OFF_HBUF  (OFF_BIASC + 8192ull)

__device__ __forceinline__ u16 f2b(float x) {   // fp32 -> bf16 RNE
    u32 u = __float_as_uint(x);
    return (u16)((u + 0x7FFFu + ((u >> 16) & 1u)) >> 16);
}
__device__ __forceinline__ float b2f(u16 b) {
    return __uint_as_float(((u32)b) << 16);
}

__global__ __launch_bounds__(256) void k_zero(float* p, int n) {
    int i = blockIdx.x * 256 + threadIdx.x;
    if (i < n) p[i] = 0.f;
}

__device__ __forceinline__ float xrep_one(float x, float m, float d, float l,
                                          float w, float bb, float em) {
    float gx = expf(-fmaxf(d * w + bb, 0.f));
    float xh = gx * l + (1.f - gx) * em;
    return m * x + (1.f - m) * xh;
}

// Elementwise precompute: x_rep and m in bf16, layout [B][T][F].
__global__ __launch_bounds__(256) void k_prep(const float* __restrict__ values,
                                              const float* __restrict__ masks,
                                              const float* __restrict__ deltas,
                                              const float* __restrict__ locf,
                                              const float* __restrict__ emean,
                                              const float* __restrict__ wx,
                                              const float* __restrict__ bxp,
                                              u16* __restrict__ xrep,
                                              u16* __restrict__ mbf) {
    int idx = blockIdx.x * 256 + threadIdx.x;   // < B*T*F/4
    int e = idx * 4;
    int f = e & 127;
    float4 xv = *(const float4*)&values[e];
    float4 mv = *(const float4*)&masks[e];
    float4 dv = *(const float4*)&deltas[e];
    float4 lv = *(const float4*)&locf[e];
    float4 wv = *(const float4*)&wx[f];
    float4 bv = *(const float4*)&bxp[f];
    float4 ev = *(const float4*)&emean[f];
    u16 o[4], mo[4];
    o[0] = f2b(xrep_one(xv.x, mv.x, dv.x, lv.x, wv.x, bv.x, ev.x));
    o[1] = f2b(xrep_one(xv.y, mv.y, dv.y, lv.y, wv.y, bv.y, ev.y));
    o[2] = f2b(xrep_one(xv.z, mv.z, dv.z, lv.z, wv.z, bv.z, ev.z));
    o[3] = f2b(xrep_one(xv.w, mv.w, dv.w, lv.w, wv.w, bv.w, ev.w));
    mo[0] = f2b(mv.x); mo[1] = f2b(mv.y); mo[2] = f2b(mv.z); mo[3] = f2b(mv.w);
    *(uint2*)&xrep[e] = *(uint2*)o;
    *(uint2*)&mbf[e]  = *(uint2*)mo;
}

// Combined weight, frag-major bf16:
// frag index = (((bx*4 + w)*2 + nt)*24 + ki)*64 + lane ; 8 bf16 (16 B) per entry.
// col c = bx*128 + w*32 + nt*16 + (lane&15); k = ki*32 + (lane>>4)*8 + j.
// gate g = c&3 (0=r,1=z,2=i_n,3=h_n), jH = c>>2. K = [x(128) | h(512) | m(128)].
__global__ __launch_bounds__(256) void k_wcomb(const float* __restrict__ W_ih,
                                               const float* __restrict__ W_hh,
                                               const float* __restrict__ b_ih,
                                               const float* __restrict__ b_hh,
                                               u16* __restrict__ wfrag,
                                               float* __restrict__ biasc) {
    int G = blockIdx.x * 256 + threadIdx.x;   // < NC*KTOT/8 = 196608
    int lane = G & 63;
    int q = G >> 6;
    int ki = q % 24; q /= 24;
    int nt = q & 1;  q >>= 1;
    int wv = q & 3;  q >>= 2;
    int bx = q;                                // 0..15
    int c = bx * 128 + wv * 32 + nt * 16 + (lane & 15);
    int kbase = ki * 32 + (lane >> 4) * 8;
    int g = c & 3, jH = c >> 2;
    u16 o[8];
#pragma unroll
    for (int j = 0; j < 8; ++j) {
        int k = kbase + j;
        float w;
        if (g < 3) {
            w = W_ih[(size_t)(g * Hh + jH) * KTOT + k];
            if (g < 2 && k >= Ff && k < Ff + Hh) w += W_hh[(size_t)(g * Hh + jH) * Hh + (k - Ff)];
        } else {
            w = (k >= Ff && k < Ff + Hh) ? W_hh[(size_t)(2 * Hh + jH) * Hh + (k - Ff)] : 0.f;
        }
        o[j] = f2b(w);
    }
    *(uint4*)&wfrag[(size_t)G * 8] = *(uint4*)o;
    if (ki == 0 && (lane >> 4) == 0) {
        float bv;
        if (g == 0)      bv = b_ih[jH] + b_hh[jH];
        else if (g == 1) bv = b_ih[Hh + jH] + b_hh[Hh + jH];
        else if (g == 2) bv = b_ih[2 * Hh + jH];
        else             bv = b_hh[2 * Hh + jH];
        biasc[c] = bv;
    }
}

// gamma_h precompute (fp32 compute, bf16 store): [T*B rows] x [H cols], K=128.
__global__ __launch_bounds__(256) void k_gamma(const float* __restrict__ deltas,
                                               const float* __restrict__ Wh,
                                               const float* __restrict__ bh,
                                               u16* __restrict__ gamma) {
    __shared__ float A_s[64][68];
    __shared__ float B_s[64][68];
    int tid = threadIdx.x;
    int tx = tid & 15, ty = tid >> 4;
    int bt0 = blockIdx.x * 64;
    int c0  = blockIdx.y * 64;

    float acc[4][4];
#pragma unroll
    for (int i = 0; i < 4; ++i)
#pragma unroll
        for (int j = 0; j < 4; ++j) acc[i][j] = 0.f;

    for (int kc = 0; kc < 2; ++kc) {
#pragma unroll
        for (int s = 0; s < 4; ++s) {
            int v = tid + s * 256;
            int row = v >> 4, c4 = v & 15, kk = c4 * 4;
            int bt = bt0 + row;
            int b = bt & 255, tt = bt >> 8;
            float4 a = *(const float4*)&deltas[b * (Tt * Ff) + tt * Ff + kc * 64 + kk];
            *(float4*)&A_s[row][kk] = a;
        }
#pragma unroll
        for (int s = 0; s < 4; ++s) {
            int v = tid + s * 256;
            int col = v >> 4, c4 = v & 15, kk = c4 * 4;
            float4 w = *(const float4*)&Wh[(c0 + col) * Ff + kc * 64 + kk];
            *(float4*)&B_s[col][kk] = w;
        }
        __syncthreads();
#pragma unroll
        for (int kk = 0; kk < 64; kk += 4) {
            float4 a[4], b[4];
#pragma unroll
            for (int i = 0; i < 4; ++i) a[i] = *(const float4*)&A_s[4 * ty + i][kk];
#pragma unroll
            for (int j = 0; j < 4; ++j) b[j] = *(const float4*)&B_s[4 * tx + j][kk];
#pragma unroll
            for (int i = 0; i < 4; ++i)
#pragma unroll
                for (int j = 0; j < 4; ++j) {
                    acc[i][j] += a[i].x * b[j].x;
                    acc[i][j] += a[i].y * b[j].y;
                    acc[i][j] += a[i].z * b[j].z;
                    acc[i][j] += a[i].w * b[j].w;
                }
        }
        __syncthreads();
    }
#pragma unroll
    for (int i = 0; i < 4; ++i) {
        int bt = bt0 + 4 * ty + i;
        u16 o[4];
#pragma unroll
        for (int j = 0; j < 4; ++j) {
            int col = c0 + 4 * tx + j;
            float x = acc[i][j] + bh[col];
            o[j] = f2b(expf(-fmaxf(x, 0.f)));
        }
        *(uint2*)&gamma[(size_t)bt * Hh + c0 + 4 * tx] = *(uint2*)o;
    }
}

// Per-step MFMA kernel. Block: 16 batch-rows x 128 weight-cols. Grid (16,16).
// B-frags resident in VGPRs (48/wave), A staged frag-major in LDS.
__global__ __launch_bounds__(256, 1) void k_step(int t,
                                                 const u16* __restrict__ xrep,
                                                 const u16* __restrict__ mbf,
                                                 const u16* __restrict__ gamma,
                                                 const u16* __restrict__ wfrag,
                                                 const float* __restrict__ biasc,
                                                 const float* __restrict__ hprev,
                                                 float* __restrict__ hnext,
                                                 float* __restrict__ hs,
                                                 float* __restrict__ hlast) {
    __shared__ u16  A_s[24 * 64 * 8];   // 24.6 KB, frag-major
    __shared__ float E_s[16][132];      // 8.45 KB, gate preacts

    int tid = threadIdx.x;
    int lane = tid & 63, w = tid >> 6;
    int bx = blockIdx.x;   // col group (16)
    int by = blockIdx.y;   // row group (16)
    int r0 = by * 16;

    // ---- B fragments: 2 N-tiles x 24 k-iters, coalesced from frag-major wfrag ----
    uint4 Bf[2][24];
    const uint4* wf4 = (const uint4*)wfrag;
#pragma unroll
    for (int nt = 0; nt < 2; ++nt)
#pragma unroll
        for (int ki = 0; ki < 24; ++ki)
            Bf[nt][ki] = wf4[(size_t)((((bx * 4 + w) * 2 + nt) * 24 + ki) * 64 + lane)];

    // ---- stage A tile (16 rows x 768 K bf16) in frag-major order ----
#pragma unroll
    for (int s = 0; s < 6; ++s) {
        int G = tid + s * 256;            // < 1536
        int ki = G >> 6;                  // wave-uniform
        int ls = G & 63;
        int row = ls & 15;
        int kbase = ki * 32 + (ls >> 4) * 8;
        int b = r0 + row;
        uint4 out;
        if (kbase < 128) {
            out = *(const uint4*)&xrep[(size_t)b * (Tt * Ff) + t * Ff + kbase];
        } else if (kbase < 640) {
            int kh = kbase - 128;
            const float* hp = &hprev[b * Hh + kh];
            float4 h0 = *(const float4*)hp;
            float4 h1 = *(const float4*)(hp + 4);
            u16 g[8];
            *(uint4*)g = *(const uint4*)&gamma[((size_t)t * Bb + b) * Hh + kh];
            u16 o[8];
            o[0] = f2b(h0.x * b2f(g[0])); o[1] = f2b(h0.y * b2f(g[1]));
            o[2] = f2b(h0.z * b2f(g[2])); o[3] = f2b(h0.w * b2f(g[3]));
            o[4] = f2b(h1.x * b2f(g[4])); o[5] = f2b(h1.y * b2f(g[5]));
            o[6] = f2b(h1.z * b2f(g[6])); o[7] = f2b(h1.w * b2f(g[7]));
            out = *(uint4*)o;
        } else {
            out = *(const uint4*)&mbf[(size_t)b * (Tt * Ff) + t * Ff + (kbase - 640)];
        }
        *(uint4*)&A_s[G * 8] = out;
    }
    __syncthreads();

    // ---- MFMA loop: 24 k-iters x 2 N-tiles ----
    f4v acc0 = {0.f, 0.f, 0.f, 0.f};
    f4v acc1 = {0.f, 0.f, 0.f, 0.f};
#pragma unroll
    for (int ki = 0; ki < 24; ++ki) {
        s8v a = *(const s8v*)&A_s[(ki * 64 + lane) * 8];
        acc0 = __builtin_amdgcn_mfma_f32_16x16x32_bf16(a, __builtin_bit_cast(s8v, Bf[0][ki]), acc0, 0, 0, 0);
        acc1 = __builtin_amdgcn_mfma_f32_16x16x32_bf16(a, __builtin_bit_cast(s8v, Bf[1][ki]), acc1, 0, 0, 0);
    }

    // ---- C layout (row=(lane>>4)*4+reg, col=lane&15) -> LDS ----
    {
        int colb = w * 32 + (lane & 15);
        int rq = (lane >> 4) * 4;
#pragma unroll
        for (int r = 0; r < 4; ++r) {
            E_s[rq + r][colb]      = acc0[r];
            E_s[rq + r][colb + 16] = acc1[r];
        }
    }
    __syncthreads();

    // ---- gates + h update: 512 (b,colH) items, 2 per thread ----
#pragma unroll
    for (int s = 0; s < 2; ++s) {
        int i = tid * 2 + s;
        int bl = i >> 5, jh = i & 31;
        int b = r0 + bl;
        int JH = bx * 32 + jh;
        float4 p  = *(const float4*)&E_s[bl][jh * 4];
        float4 bi = *(const float4*)&biasc[JH * 4];
        float rr = 1.f / (1.f + expf(-(p.x + bi.x)));
        float zz = 1.f / (1.f + expf(-(p.y + bi.y)));
        float nn = tanhf(p.z + bi.z + rr * (p.w + bi.w));
        float hp = hprev[b * Hh + JH] * b2f(gamma[((size_t)t * Bb + b) * Hh + JH]);
        float hn = (1.f - zz) * nn + zz * hp;
        hnext[b * Hh + JH] = hn;
        hs[(size_t)b * (Tt * Hh) + (size_t)t * Hh + JH] = hn;
        if (t == Tt - 1) hlast[(size_t)b * Hh + JH] = hn;
    }
}

extern "C" void kernel_launch(void* const* d_in, const int* in_sizes, int n_in,
                              void* d_out, int out_size, void* d_ws, size_t ws_size,
                              hipStream_t stream) {
    const float* values = (const float*)d_in[0];
    const float* masks  = (const float*)d_in[1];
    const float* deltas = (const float*)d_in[2];
    const float* emean  = (const float*)d_in[3];
    const float* locf   = (const float*)d_in[4];
    const float* wx     = (const float*)d_in[5];
    const float* bxp    = (const float*)d_in[6];
    const float* Wh     = (const float*)d_in[7];
    const float* bh     = (const float*)d_in[8];
    const float* W_ih   = (const float*)d_in[9];
    const float* W_hh   = (const float*)d_in[10];
    const float* b_ih   = (const float*)d_in[11];
    const float* b_hh   = (const float*)d_in[12];

    char* wsb   = (char*)d_ws;
    u16*  gamma = (u16*)(wsb + OFF_GAMMA);
    u16*  xrep  = (u16*)(wsb + OFF_XREP);
    u16*  mbf   = (u16*)(wsb + OFF_MBF);
    u16*  wfrag = (u16*)(wsb + OFF_WFRAG);
    float* biasc = (float*)(wsb + OFF_BIASC);
    float* hbuf  = (float*)(wsb + OFF_HBUF);
    float* hs    = (float*)d_out;
    float* hlast = hs + (size_t)Bb * Tt * Hh;

    k_zero<<<(2 * Bb * Hh) / 256, 256, 0, stream>>>(hbuf, 2 * Bb * Hh);
    k_prep<<<(Bb * Tt * Ff / 4) / 256, 256, 0, stream>>>(values, masks, deltas, locf,
                                                         emean, wx, bxp, xrep, mbf);
    k_gamma<<<dim3((Tt * Bb) / 64, Hh / 64), 256, 0, stream>>>(deltas, Wh, bh, gamma);
    k_wcomb<<<(NC * KTOT / 8) / 256, 256, 0, stream>>>(W_ih, W_hh, b_ih, b_hh, wfrag, biasc);

    for (int t = 0; t < Tt; ++t) {
        float* hprev = hbuf + (t & 1) * (Bb * Hh);
        float* hnext = hbuf + ((t + 1) & 1) * (Bb * Hh);
        k_step<<<dim3(16, 16), 256, 0, stream>>>(t, xrep, mbf, gamma, wfrag, biasc,
                                                 hprev, hnext, hs, hlast);
    }
}